// Round 1
// baseline (895.395 us; speedup 1.0000x reference)
//
#include <hip/hip_runtime.h>
#include <hip/hip_bf16.h>
#include <cstdint>
#include <cstddef>

typedef unsigned short u16;
typedef unsigned int u32;
typedef short short8 __attribute__((ext_vector_type(8)));
typedef __bf16 bf16x8 __attribute__((ext_vector_type(8)));
typedef float v4f __attribute__((ext_vector_type(4)));
typedef float v16f __attribute__((ext_vector_type(16)));

#define NSAMP 65536
#define FEAT_PAD 1824   // 57 * 32 (1808 padded; pad cols of W1t are zero)

__device__ __forceinline__ u16 f2bf(float f) {
  union { float f; u32 u; } v; v.f = f;
  u32 r = (v.u + 0x7FFFu + ((v.u >> 16) & 1u)) >> 16;  // RTNE
  return (u16)r;
}
__device__ __forceinline__ float bf2f(u16 h) {
  union { u32 u; float f; } v; v.u = ((u32)h) << 16;
  return v.f;
}

__device__ __forceinline__ v4f mfma16(short8 a, short8 b, v4f c) {
  return __builtin_amdgcn_mfma_f32_16x16x32_bf16(
      __builtin_bit_cast(bf16x8, a), __builtin_bit_cast(bf16x8, b), c, 0, 0, 0);
}
__device__ __forceinline__ v16f mfma32(short8 a, short8 b, v16f c) {
  return __builtin_amdgcn_mfma_f32_32x32x16_bf16(
      __builtin_bit_cast(bf16x8, a), __builtin_bit_cast(bf16x8, b), c, 0, 0, 0);
}

// ---------------------------------------------------------------------------
// Weight prep: transpose + bf16-cast W1/W2/W3 (B^T layout for MFMA B-frags).
// W1t[n][k] (k padded to 1824 with zeros), W2t[n][k], W3t[n][k].
// ---------------------------------------------------------------------------
__global__ void prep_kernel(const float* __restrict__ W1, const float* __restrict__ W2,
                            const float* __restrict__ W3,
                            u16* __restrict__ w1t, u16* __restrict__ w2t, u16* __restrict__ w3t) {
  int idx = blockIdx.x * 256 + threadIdx.x;
  if (idx < 256 * FEAT_PAD) {
    int n = idx / FEAT_PAD, k = idx % FEAT_PAD;
    w1t[idx] = (k < 1808) ? f2bf(W1[(size_t)k * 256 + n]) : (u16)0;
  }
  if (idx < 128 * 256) {
    int n = idx / 256, k = idx % 256;
    w2t[idx] = f2bf(W2[k * 128 + n]);
  }
  if (idx < 64 * 128) {
    int n = idx / 128, k = idx % 128;
    w3t[idx] = f2bf(W3[k * 64 + n]);
  }
}

// ---------------------------------------------------------------------------
// Feature kernel: per sample write bf16 feats[1824]:
//   [0,512)    x
//   [512,1536) Gc = P^T P   (32x32, one v_mfma_f32_32x32x16_bf16)
//   [1536,1792) Gr = P P^T  (16x16, one v_mfma_f32_16x16x32_bf16)
//   [1792,1808) singular values (filled by svd_kernel)
//   [1808,1824) zeros
// A-frag and B-frag of X·X^T products are identical register content.
// ---------------------------------------------------------------------------
__global__ __launch_bounds__(256) void feat_kernel(const float* __restrict__ x,
                                                   u16* __restrict__ feats) {
  const int lane = threadIdx.x & 63;
  const int wid = ((blockIdx.x * 256) + threadIdx.x) >> 6;  // 0..4095
  const int l15 = lane & 15, l31 = lane & 31, q4 = lane >> 4, q2 = lane >> 5;
  const int pbase = l15 * 32 + q4 * 8;  // fragP element offset (contig 8)

  for (int it = 0; it < 16; ++it) {
    const int s = wid * 16 + it;
    const float* xs = x + (size_t)s * 512;
    // fragP: P[m=l15][k=q4*8+j] = x[m*32+k] — contiguous 8 floats
    float4 p0 = *(const float4*)(xs + pbase);
    float4 p1 = *(const float4*)(xs + pbase + 4);
    // fragT: P^T[m=l31][k=q2*8+j] = x[k*32+m] — stride-32 gather (wave-coalesced)
    float t[8];
#pragma unroll
    for (int j = 0; j < 8; ++j) t[j] = xs[(q2 * 8 + j) * 32 + l31];

    short8 fp, ft;
    fp[0] = (short)f2bf(p0.x); fp[1] = (short)f2bf(p0.y);
    fp[2] = (short)f2bf(p0.z); fp[3] = (short)f2bf(p0.w);
    fp[4] = (short)f2bf(p1.x); fp[5] = (short)f2bf(p1.y);
    fp[6] = (short)f2bf(p1.z); fp[7] = (short)f2bf(p1.w);
#pragma unroll
    for (int j = 0; j < 8; ++j) ft[j] = (short)f2bf(t[j]);

    v4f accR; v16f accC;
#pragma unroll
    for (int r = 0; r < 4; ++r) accR[r] = 0.f;
#pragma unroll
    for (int r = 0; r < 16; ++r) accC[r] = 0.f;
    accR = mfma16(fp, fp, accR);   // Gr = P P^T
    accC = mfma32(ft, ft, accC);   // Gc = P^T P

    u16* fs = feats + (size_t)s * FEAT_PAD;
    *(short8*)(fs + pbase) = fp;   // x part (bf16)
#pragma unroll
    for (int r = 0; r < 16; ++r) {  // C/D 32x32: row=(r&3)+8*(r>>2)+4*(lane>>5), col=lane&31
      int row = (r & 3) + 8 * (r >> 2) + 4 * q2;
      fs[512 + row * 32 + l31] = f2bf(accC[r]);
    }
#pragma unroll
    for (int r = 0; r < 4; ++r) {   // C/D 16x16: row=(lane>>4)*4+r, col=lane&15
      fs[1536 + (q4 * 4 + r) * 16 + l15] = f2bf(accR[r]);
    }
    if (lane < 2) {  // zero pad [1808,1824)
      short8 z;
#pragma unroll
      for (int j = 0; j < 8; ++j) z[j] = 0;
      *(short8*)(fs + 1808 + lane * 8) = z;
    }
  }
}

// ---------------------------------------------------------------------------
// SVD kernel: one thread per sample. Householder tridiagonalization of the
// 16x16 gram (read back as bf16 from feats) + Sturm bisection for eigenvalues.
// sv[i] = sqrt(lambda[15-i]) (descending), written into feats[1792:1808).
// ---------------------------------------------------------------------------
__global__ __launch_bounds__(64) void svd_kernel(u16* __restrict__ feats) {
  const int s = blockIdx.x * 64 + threadIdx.x;
  const u16* g = feats + (size_t)s * FEAT_PAD + 1536;
  float a[136];  // packed lower triangle, A(i,j)=a[i*(i+1)/2+j], i>=j
#define AA(i, j) a[(i) * ((i) + 1) / 2 + (j)]
#pragma unroll
  for (int i = 0; i < 16; ++i)
#pragma unroll
    for (int j = 0; j <= i; ++j) AA(i, j) = bf2f(g[i * 16 + j]);

  float d[16], e[16];
  e[0] = 0.f;
#pragma unroll
  for (int i = 15; i >= 1; --i) {
    const int l = i - 1;
    if (l > 0) {
      float scale = 0.f, h = 0.f;
#pragma unroll
      for (int k = 0; k <= l; ++k) scale += fabsf(AA(i, k));
      if (scale == 0.f) {
        e[i] = AA(i, l);
      } else {
        float inv = 1.f / scale;
#pragma unroll
        for (int k = 0; k <= l; ++k) { AA(i, k) *= inv; h += AA(i, k) * AA(i, k); }
        float f = AA(i, l);
        float gg = (f >= 0.f) ? -sqrtf(h) : sqrtf(h);
        e[i] = scale * gg;
        h -= f * gg;
        AA(i, l) = f - gg;
        f = 0.f;
#pragma unroll
        for (int j = 0; j <= l; ++j) {
          float g2 = 0.f;
#pragma unroll
          for (int k = 0; k <= j; ++k) g2 += AA(j, k) * AA(i, k);
#pragma unroll
          for (int k = j + 1; k <= l; ++k) g2 += AA(k, j) * AA(i, k);
          e[j] = g2 / h;
          f += e[j] * AA(i, j);
        }
        float hh = f / (h + h);
#pragma unroll
        for (int j = 0; j <= l; ++j) {
          float fj = AA(i, j);
          float gj = e[j] - hh * fj;
          e[j] = gj;
#pragma unroll
          for (int k = 0; k <= j; ++k) AA(j, k) -= fj * e[k] + gj * AA(i, k);
        }
      }
    } else {
      e[i] = AA(i, l);
    }
  }
#pragma unroll
  for (int i = 0; i < 16; ++i) d[i] = AA(i, i);
#undef AA

  float e2[16];
  e2[0] = 0.f;
#pragma unroll
  for (int k = 1; k < 16; ++k) e2[k] = e[k] * e[k] + 1e-30f;
  float glo = 1e30f, ghi = -1e30f;
#pragma unroll
  for (int k = 0; k < 16; ++k) {
    float r1 = (k >= 1) ? fabsf(e[k]) : 0.f;
    float r2 = (k < 15) ? fabsf(e[k + 1]) : 0.f;
    glo = fminf(glo, d[k] - r1 - r2);
    ghi = fmaxf(ghi, d[k] + r1 + r2);
  }
  float lob[16], hib[16];
#pragma unroll
  for (int t = 0; t < 16; ++t) { lob[t] = glo; hib[t] = ghi; }
#pragma unroll 1
  for (int iter = 0; iter < 24; ++iter) {
#pragma unroll
    for (int t = 0; t < 16; ++t) {
      float m = 0.5f * (lob[t] + hib[t]);
      float q = d[0] - m;
      int cnt = (q < 0.f) ? 1 : 0;
#pragma unroll
      for (int k = 1; k < 16; ++k) {
        q = d[k] - m - e2[k] * __builtin_amdgcn_rcpf(q);
        cnt += (q < 0.f) ? 1 : 0;
      }
      if (cnt > t) hib[t] = m; else lob[t] = m;
    }
  }
  u16* sv = feats + (size_t)s * FEAT_PAD + 1792;
#pragma unroll
  for (int t = 0; t < 16; ++t) {
    float lam = 0.5f * (lob[15 - t] + hib[15 - t]);
    sv[t] = f2bf(sqrtf(fmaxf(lam, 0.f)));
  }
}

// ---------------------------------------------------------------------------
// GEMM1: h1 = relu(feats @ W1 + b1).  M=65536, K=1824, N=256.
// Tile 64x256 per 256-thread block (feats read once from HBM; W1t from L2).
// ---------------------------------------------------------------------------
__global__ __launch_bounds__(256) void gemm1_kernel(const u16* __restrict__ feats,
                                                    const u16* __restrict__ w1t,
                                                    const float* __restrict__ b1,
                                                    u16* __restrict__ h1) {
  __shared__ __align__(16) u16 At[64 * 32];    // 4 KB
  __shared__ __align__(16) u16 Bt[256 * 32];   // 16 KB
  const int tid = threadIdx.x;
  const int lane = tid & 63, wv = tid >> 6;
  const int l15 = lane & 15, q4 = lane >> 4;
  const int m0 = blockIdx.x * 64;
  const int wm = (wv & 1) * 32;
  const int wn = (wv >> 1) * 128;

  v4f acc[2][8];
#pragma unroll
  for (int mt = 0; mt < 2; ++mt)
#pragma unroll
    for (int nt = 0; nt < 8; ++nt)
#pragma unroll
      for (int r = 0; r < 4; ++r) acc[mt][nt][r] = 0.f;

  const int arow = tid >> 2, aq = tid & 3;
  for (int k0 = 0; k0 < FEAT_PAD; k0 += 32) {
    uint4 av = *(const uint4*)(feats + (size_t)(m0 + arow) * FEAT_PAD + k0 + aq * 8);
    uint4 bv[4];
#pragma unroll
    for (int p = 0; p < 4; ++p) {
      int c = p * 256 + tid;
      bv[p] = *(const uint4*)(w1t + (size_t)(c >> 2) * FEAT_PAD + k0 + (c & 3) * 8);
    }
    __syncthreads();  // prev iter LDS reads done
    *(uint4*)(At + tid * 8) = av;
#pragma unroll
    for (int p = 0; p < 4; ++p) *(uint4*)(Bt + (p * 256 + tid) * 8) = bv[p];
    __syncthreads();  // tiles ready

    short8 af[2], bfr[8];
#pragma unroll
    for (int mt = 0; mt < 2; ++mt)
      af[mt] = *(const short8*)(At + (wm + mt * 16 + l15) * 32 + q4 * 8);
#pragma unroll
    for (int nt = 0; nt < 8; ++nt)
      bfr[nt] = *(const short8*)(Bt + (wn + nt * 16 + l15) * 32 + q4 * 8);
#pragma unroll
    for (int mt = 0; mt < 2; ++mt)
#pragma unroll
      for (int nt = 0; nt < 8; ++nt)
        acc[mt][nt] = mfma16(af[mt], bfr[nt], acc[mt][nt]);
  }
#pragma unroll
  for (int mt = 0; mt < 2; ++mt)
#pragma unroll
    for (int nt = 0; nt < 8; ++nt) {
      int col = wn + nt * 16 + l15;
      float bias = b1[col];
#pragma unroll
      for (int r = 0; r < 4; ++r) {
        int row = m0 + wm + mt * 16 + q4 * 4 + r;
        h1[(size_t)row * 256 + col] = f2bf(fmaxf(acc[mt][nt][r] + bias, 0.f));
      }
    }
}

// ---------------------------------------------------------------------------
// GEMM23: fused layers 2-4.  Per block: 128 samples.
// h2 = relu(h1@W2+b2) -> LDS(bf16) -> h3 = relu(h2@W3+b3) -> out = h3@W4+b4.
// ---------------------------------------------------------------------------
__global__ __launch_bounds__(256) void gemm23_kernel(
    const u16* __restrict__ h1, const u16* __restrict__ w2t, const float* __restrict__ b2,
    const u16* __restrict__ w3t, const float* __restrict__ b3,
    const float* __restrict__ w4, const float* __restrict__ b4, float* __restrict__ out) {
  __shared__ __align__(16) u16 At[128 * 32];   // 8 KB
  __shared__ __align__(16) u16 Bt[128 * 32];   // 8 KB
  __shared__ __align__(16) u16 B3[64 * 128];   // 16 KB (all of W3t)
  __shared__ __align__(16) u16 H2[128 * 136];  // 34 KB (pad 136 vs 128)
  const int tid = threadIdx.x, lane = tid & 63, wv = tid >> 6;
  const int l15 = lane & 15, q4 = lane >> 4;
  const int m0 = blockIdx.x * 128;

  // stage W3t once
#pragma unroll
  for (int p = 0; p < 4; ++p) {
    int c = p * 256 + tid;
    *(uint4*)(B3 + c * 8) = *(const uint4*)(w3t + c * 8);
  }

  v4f acc[2][8];
#pragma unroll
  for (int mt = 0; mt < 2; ++mt)
#pragma unroll
    for (int nt = 0; nt < 8; ++nt)
#pragma unroll
      for (int r = 0; r < 4; ++r) acc[mt][nt][r] = 0.f;

  const int arow = tid >> 2, aq = tid & 3;
  for (int k0 = 0; k0 < 256; k0 += 32) {
    uint4 av[2], bv[2];
    av[0] = *(const uint4*)(h1 + (size_t)(m0 + arow) * 256 + k0 + aq * 8);
    av[1] = *(const uint4*)(h1 + (size_t)(m0 + 64 + arow) * 256 + k0 + aq * 8);
    bv[0] = *(const uint4*)(w2t + (size_t)arow * 256 + k0 + aq * 8);
    bv[1] = *(const uint4*)(w2t + (size_t)(64 + arow) * 256 + k0 + aq * 8);
    __syncthreads();
    *(uint4*)(At + tid * 8) = av[0];
    *(uint4*)(At + (256 + tid) * 8) = av[1];
    *(uint4*)(Bt + tid * 8) = bv[0];
    *(uint4*)(Bt + (256 + tid) * 8) = bv[1];
    __syncthreads();

    short8 af[2], bfr[8];
#pragma unroll
    for (int mt = 0; mt < 2; ++mt)
      af[mt] = *(const short8*)(At + (wv * 32 + mt * 16 + l15) * 32 + q4 * 8);
#pragma unroll
    for (int nt = 0; nt < 8; ++nt)
      bfr[nt] = *(const short8*)(Bt + (nt * 16 + l15) * 32 + q4 * 8);
#pragma unroll
    for (int mt = 0; mt < 2; ++mt)
#pragma unroll
      for (int nt = 0; nt < 8; ++nt)
        acc[mt][nt] = mfma16(af[mt], bfr[nt], acc[mt][nt]);
  }
  __syncthreads();
  // h2 -> LDS (relu + bias, bf16)
#pragma unroll
  for (int mt = 0; mt < 2; ++mt)
#pragma unroll
    for (int nt = 0; nt < 8; ++nt) {
      int c = nt * 16 + l15;
      float bias = b2[c];
#pragma unroll
      for (int r = 0; r < 4; ++r) {
        int rl = wv * 32 + mt * 16 + q4 * 4 + r;
        H2[rl * 136 + c] = f2bf(fmaxf(acc[mt][nt][r] + bias, 0.f));
      }
    }
  __syncthreads();

  // layer 3: K=128, N=64
  v4f acc2[2][4];
#pragma unroll
  for (int mt = 0; mt < 2; ++mt)
#pragma unroll
    for (int nt = 0; nt < 4; ++nt)
#pragma unroll
      for (int r = 0; r < 4; ++r) acc2[mt][nt][r] = 0.f;
#pragma unroll
  for (int kk = 0; kk < 4; ++kk) {
    short8 af2[2], bf2[4];
#pragma unroll
    for (int mt = 0; mt < 2; ++mt)
      af2[mt] = *(const short8*)(H2 + (wv * 32 + mt * 16 + l15) * 136 + kk * 32 + q4 * 8);
#pragma unroll
    for (int nt = 0; nt < 4; ++nt)
      bf2[nt] = *(const short8*)(B3 + (nt * 16 + l15) * 128 + kk * 32 + q4 * 8);
#pragma unroll
    for (int mt = 0; mt < 2; ++mt)
#pragma unroll
      for (int nt = 0; nt < 4; ++nt)
        acc2[mt][nt] = mfma16(af2[mt], bf2[nt], acc2[mt][nt]);
  }

  // layer 4: relu(h3) dot w4, shuffle-reduce over the 16 column lanes
  float b4v = b4[0];
#pragma unroll
  for (int mt = 0; mt < 2; ++mt)
#pragma unroll
    for (int r = 0; r < 4; ++r) {
      float p = 0.f;
#pragma unroll
      for (int nt = 0; nt < 4; ++nt) {
        int c = nt * 16 + l15;
        float h3 = fmaxf(acc2[mt][nt][r] + b3[c], 0.f);
        p += h3 * w4[c];
      }
      p += __shfl_xor(p, 1);
      p += __shfl_xor(p, 2);
      p += __shfl_xor(p, 4);
      p += __shfl_xor(p, 8);
      if (l15 == 0) {
        int row = m0 + wv * 32 + mt * 16 + q4 * 4 + r;
        out[row] = p + b4v;
      }
    }
}

// ---------------------------------------------------------------------------
extern "C" void kernel_launch(void* const* d_in, const int* in_sizes, int n_in,
                              void* d_out, int out_size, void* d_ws, size_t ws_size,
                              hipStream_t stream) {
  const float* x  = (const float*)d_in[0];
  const float* W1 = (const float*)d_in[1];
  const float* b1 = (const float*)d_in[2];
  const float* W2 = (const float*)d_in[3];
  const float* b2 = (const float*)d_in[4];
  const float* W3 = (const float*)d_in[5];
  const float* b3 = (const float*)d_in[6];
  const float* W4 = (const float*)d_in[7];
  const float* b4 = (const float*)d_in[8];
  float* out = (float*)d_out;

  char* ws = (char*)d_ws;
  u16* feats = (u16*)ws;                                  // 65536*1824*2 = 239,075,328
  u16* h1    = (u16*)(ws + 239075328ull);                 // 65536*256*2  =  33,554,432
  u16* w1t   = (u16*)(ws + 239075328ull + 33554432ull);   // 256*1824*2   =     933,888
  u16* w2t   = (u16*)(ws + 239075328ull + 33554432ull + 933888ull);          // 65,536
  u16* w3t   = (u16*)(ws + 239075328ull + 33554432ull + 933888ull + 65536ull); // 16,384
  // total ws needed: 273,645,568 bytes

  prep_kernel<<<1824, 256, 0, stream>>>(W1, W2, W3, w1t, w2t, w3t);
  feat_kernel<<<1024, 256, 0, stream>>>(x, feats);
  svd_kernel<<<1024, 64, 0, stream>>>(feats);
  gemm1_kernel<<<1024, 256, 0, stream>>>(feats, w1t, b1, h1);
  gemm23_kernel<<<512, 256, 0, stream>>>(h1, w2t, b2, w3t, b3, W4, b4, out);
}

// Round 2
// 584.994 us; speedup vs baseline: 1.5306x; 1.5306x over previous
//
#include <hip/hip_runtime.h>
#include <hip/hip_bf16.h>
#include <cstdint>
#include <cstddef>

typedef unsigned short u16;
typedef unsigned int u32;
typedef short short8 __attribute__((ext_vector_type(8)));
typedef __bf16 bf16x8 __attribute__((ext_vector_type(8)));
typedef float v4f __attribute__((ext_vector_type(4)));
typedef float v16f __attribute__((ext_vector_type(16)));

#define NSAMP 65536
#define FEAT_PAD 1824   // 57 * 32 (1808 padded; pad cols of W1t are zero)

__device__ __forceinline__ u16 f2bf(float f) {
  union { float f; u32 u; } v; v.f = f;
  u32 r = (v.u + 0x7FFFu + ((v.u >> 16) & 1u)) >> 16;  // RTNE
  return (u16)r;
}
__device__ __forceinline__ float bf2f(u16 h) {
  union { u32 u; float f; } v; v.u = ((u32)h) << 16;
  return v.f;
}

__device__ __forceinline__ v4f mfma16(short8 a, short8 b, v4f c) {
  return __builtin_amdgcn_mfma_f32_16x16x32_bf16(
      __builtin_bit_cast(bf16x8, a), __builtin_bit_cast(bf16x8, b), c, 0, 0, 0);
}
__device__ __forceinline__ v16f mfma32(short8 a, short8 b, v16f c) {
  return __builtin_amdgcn_mfma_f32_32x32x16_bf16(
      __builtin_bit_cast(bf16x8, a), __builtin_bit_cast(bf16x8, b), c, 0, 0, 0);
}

// async global->LDS, 16 B per lane; LDS dest = wave-uniform base + lane*16
typedef __attribute__((address_space(1))) const void* gas_ptr;
typedef __attribute__((address_space(3))) void* las_ptr;
__device__ __forceinline__ void gl_lds16(const void* g, void* l) {
  __builtin_amdgcn_global_load_lds((gas_ptr)g, (las_ptr)l, 16, 0, 0);
}

// ---------------------------------------------------------------------------
// Weight prep: transpose + bf16-cast W1/W2/W3 (B^T layout for MFMA B-frags).
// ---------------------------------------------------------------------------
__global__ void prep_kernel(const float* __restrict__ W1, const float* __restrict__ W2,
                            const float* __restrict__ W3,
                            u16* __restrict__ w1t, u16* __restrict__ w2t, u16* __restrict__ w3t) {
  int idx = blockIdx.x * 256 + threadIdx.x;
  if (idx < 256 * FEAT_PAD) {
    int n = idx / FEAT_PAD, k = idx % FEAT_PAD;
    w1t[idx] = (k < 1808) ? f2bf(W1[(size_t)k * 256 + n]) : (u16)0;
  }
  if (idx < 128 * 256) {
    int n = idx / 256, k = idx % 256;
    w2t[idx] = f2bf(W2[k * 128 + n]);
  }
  if (idx < 64 * 128) {
    int n = idx / 128, k = idx % 128;
    w3t[idx] = f2bf(W3[k * 64 + n]);
  }
}

// ---------------------------------------------------------------------------
// Feature kernel (unchanged from R1, validated): bf16 feats[1824] per sample.
// ---------------------------------------------------------------------------
__global__ __launch_bounds__(256) void feat_kernel(const float* __restrict__ x,
                                                   u16* __restrict__ feats) {
  const int lane = threadIdx.x & 63;
  const int wid = ((blockIdx.x * 256) + threadIdx.x) >> 6;  // 0..4095
  const int l15 = lane & 15, l31 = lane & 31, q4 = lane >> 4, q2 = lane >> 5;
  const int pbase = l15 * 32 + q4 * 8;

  for (int it = 0; it < 16; ++it) {
    const int s = wid * 16 + it;
    const float* xs = x + (size_t)s * 512;
    float4 p0 = *(const float4*)(xs + pbase);
    float4 p1 = *(const float4*)(xs + pbase + 4);
    float t[8];
#pragma unroll
    for (int j = 0; j < 8; ++j) t[j] = xs[(q2 * 8 + j) * 32 + l31];

    short8 fp, ft;
    fp[0] = (short)f2bf(p0.x); fp[1] = (short)f2bf(p0.y);
    fp[2] = (short)f2bf(p0.z); fp[3] = (short)f2bf(p0.w);
    fp[4] = (short)f2bf(p1.x); fp[5] = (short)f2bf(p1.y);
    fp[6] = (short)f2bf(p1.z); fp[7] = (short)f2bf(p1.w);
#pragma unroll
    for (int j = 0; j < 8; ++j) ft[j] = (short)f2bf(t[j]);

    v4f accR; v16f accC;
#pragma unroll
    for (int r = 0; r < 4; ++r) accR[r] = 0.f;
#pragma unroll
    for (int r = 0; r < 16; ++r) accC[r] = 0.f;
    accR = mfma16(fp, fp, accR);   // Gr = P P^T
    accC = mfma32(ft, ft, accC);   // Gc = P^T P

    u16* fs = feats + (size_t)s * FEAT_PAD;
    *(short8*)(fs + pbase) = fp;
#pragma unroll
    for (int r = 0; r < 16; ++r) {
      int row = (r & 3) + 8 * (r >> 2) + 4 * q2;
      fs[512 + row * 32 + l31] = f2bf(accC[r]);
    }
#pragma unroll
    for (int r = 0; r < 4; ++r) {
      fs[1536 + (q4 * 4 + r) * 16 + l15] = f2bf(accR[r]);
    }
    if (lane < 2) {
      short8 z;
#pragma unroll
      for (int j = 0; j < 8; ++j) z[j] = 0;
      *(short8*)(fs + 1808 + lane * 8) = z;
    }
  }
}

// ---------------------------------------------------------------------------
// SVD kernel: one thread per sample. launch_bounds(64,1) -> 512-VGPR budget,
// no scratch spill for the 136-elem packed triangle. Bisection cut to 16
// iters (sv abs err ~1e-3, tolerance ~2e-2).
// ---------------------------------------------------------------------------
__global__ __launch_bounds__(64, 1) void svd_kernel(u16* __restrict__ feats) {
  const int s = blockIdx.x * 64 + threadIdx.x;
  const u16* g = feats + (size_t)s * FEAT_PAD + 1536;
  float a[136];  // packed lower triangle
#define AA(i, j) a[(i) * ((i) + 1) / 2 + (j)]
#pragma unroll
  for (int i = 0; i < 16; ++i)
#pragma unroll
    for (int j = 0; j <= i; ++j) AA(i, j) = bf2f(g[i * 16 + j]);

  float d[16], e[16];
  e[0] = 0.f;
#pragma unroll
  for (int i = 15; i >= 1; --i) {
    const int l = i - 1;
    if (l > 0) {
      float scale = 0.f, h = 0.f;
#pragma unroll
      for (int k = 0; k <= l; ++k) scale += fabsf(AA(i, k));
      if (scale == 0.f) {
        e[i] = AA(i, l);
      } else {
        float inv = 1.f / scale;
#pragma unroll
        for (int k = 0; k <= l; ++k) { AA(i, k) *= inv; h += AA(i, k) * AA(i, k); }
        float f = AA(i, l);
        float gg = (f >= 0.f) ? -sqrtf(h) : sqrtf(h);
        e[i] = scale * gg;
        h -= f * gg;
        AA(i, l) = f - gg;
        f = 0.f;
#pragma unroll
        for (int j = 0; j <= l; ++j) {
          float g2 = 0.f;
#pragma unroll
          for (int k = 0; k <= j; ++k) g2 += AA(j, k) * AA(i, k);
#pragma unroll
          for (int k = j + 1; k <= l; ++k) g2 += AA(k, j) * AA(i, k);
          e[j] = g2 / h;
          f += e[j] * AA(i, j);
        }
        float hh = f / (h + h);
#pragma unroll
        for (int j = 0; j <= l; ++j) {
          float fj = AA(i, j);
          float gj = e[j] - hh * fj;
          e[j] = gj;
#pragma unroll
          for (int k = 0; k <= j; ++k) AA(j, k) -= fj * e[k] + gj * AA(i, k);
        }
      }
    } else {
      e[i] = AA(i, l);
    }
  }
#pragma unroll
  for (int i = 0; i < 16; ++i) d[i] = AA(i, i);
#undef AA

  float e2[16];
  e2[0] = 0.f;
#pragma unroll
  for (int k = 1; k < 16; ++k) e2[k] = e[k] * e[k] + 1e-30f;
  float ghi = -1e30f;
#pragma unroll
  for (int k = 0; k < 16; ++k) {
    float r1 = (k >= 1) ? fabsf(e[k]) : 0.f;
    float r2 = (k < 15) ? fabsf(e[k + 1]) : 0.f;
    ghi = fmaxf(ghi, d[k] + r1 + r2);
  }
  float lob[16], hib[16];
#pragma unroll
  for (int t = 0; t < 16; ++t) { lob[t] = 0.f; hib[t] = ghi; }  // gram is PSD
#pragma unroll 1
  for (int iter = 0; iter < 16; ++iter) {
#pragma unroll
    for (int t = 0; t < 16; ++t) {
      float m = 0.5f * (lob[t] + hib[t]);
      float q = d[0] - m;
      int cnt = (q < 0.f) ? 1 : 0;
#pragma unroll
      for (int k = 1; k < 16; ++k) {
        q = d[k] - m - e2[k] * __builtin_amdgcn_rcpf(q);
        cnt += (q < 0.f) ? 1 : 0;
      }
      if (cnt > t) hib[t] = m; else lob[t] = m;
    }
  }
  u16* sv = feats + (size_t)s * FEAT_PAD + 1792;
#pragma unroll
  for (int t = 0; t < 16; ++t) {
    float lam = 0.5f * (lob[15 - t] + hib[15 - t]);
    sv[t] = f2bf(sqrtf(fmaxf(lam, 0.f)));
  }
}

// ---------------------------------------------------------------------------
// GEMM1: h1 = relu(feats @ W1 + b1).  M=65536, K=1824, N=256.
// m97-style: 128x256 tile per 256-thread block (feats read ONCE from HBM),
// global_load_lds width-16 staging, LDS layout [k-group][row] so fragment
// ds_read_b128 aliasing is 2-way (free). Wave tile 64x128 = 32 MFMA/barrier.
// ---------------------------------------------------------------------------
__global__ __launch_bounds__(256, 2) void gemm1_kernel(const u16* __restrict__ feats,
                                                       const u16* __restrict__ w1t,
                                                       const float* __restrict__ b1,
                                                       u16* __restrict__ h1) {
  __shared__ __align__(16) u16 At[4 * 128 * 8];   // [q 0..3][row 0..127] * 8 elems, 8 KB
  __shared__ __align__(16) u16 Bt[4 * 256 * 8];   // [q 0..3][col 0..255] * 8 elems, 16 KB
  const int tid = threadIdx.x, lane = tid & 63, wv = tid >> 6;
  const int l15 = lane & 15, q4 = lane >> 4;
  const int m0 = blockIdx.x * 128;
  const int wm = (wv & 1) * 64, wn = (wv >> 1) * 128;

  // staging descriptors (hoisted): A 2 instrs/wave, B 4 instrs/wave
  const u16* gA[2]; u16* lA[2];
#pragma unroll
  for (int j = 0; j < 2; ++j) {
    int slot0 = (wv * 2 + j) * 64, slot = slot0 + lane;
    int q = slot >> 7, row = slot & 127;
    gA[j] = feats + (size_t)(m0 + row) * FEAT_PAD + q * 8;
    lA[j] = At + slot0 * 8;
  }
  const u16* gB[4]; u16* lB[4];
#pragma unroll
  for (int j = 0; j < 4; ++j) {
    int slot0 = (wv * 4 + j) * 64, slot = slot0 + lane;
    int q = slot >> 8, col = slot & 255;
    gB[j] = w1t + (size_t)col * FEAT_PAD + q * 8;
    lB[j] = Bt + slot0 * 8;
  }

  v4f acc[4][8];
#pragma unroll
  for (int mt = 0; mt < 4; ++mt)
#pragma unroll
    for (int nt = 0; nt < 8; ++nt)
#pragma unroll
      for (int r = 0; r < 4; ++r) acc[mt][nt][r] = 0.f;

  for (int k0 = 0; k0 < FEAT_PAD; k0 += 32) {
#pragma unroll
    for (int j = 0; j < 2; ++j) gl_lds16(gA[j] + k0, lA[j]);
#pragma unroll
    for (int j = 0; j < 4; ++j) gl_lds16(gB[j] + k0, lB[j]);
    __syncthreads();  // vmcnt(0) drain: tiles ready

    short8 af[4], bfr[8];
#pragma unroll
    for (int mt = 0; mt < 4; ++mt)
      af[mt] = *(const short8*)(At + (q4 * 128 + wm + mt * 16 + l15) * 8);
#pragma unroll
    for (int nt = 0; nt < 8; ++nt)
      bfr[nt] = *(const short8*)(Bt + (q4 * 256 + wn + nt * 16 + l15) * 8);
#pragma unroll
    for (int mt = 0; mt < 4; ++mt)
#pragma unroll
      for (int nt = 0; nt < 8; ++nt)
        acc[mt][nt] = mfma16(af[mt], bfr[nt], acc[mt][nt]);
    __syncthreads();  // frag reads done before next overwrite
  }

#pragma unroll
  for (int mt = 0; mt < 4; ++mt)
#pragma unroll
    for (int nt = 0; nt < 8; ++nt) {
      int col = wn + nt * 16 + l15;
      float bias = b1[col];
#pragma unroll
      for (int r = 0; r < 4; ++r) {
        int row = m0 + wm + mt * 16 + q4 * 4 + r;
        h1[(size_t)row * 256 + col] = f2bf(fmaxf(acc[mt][nt][r] + bias, 0.f));
      }
    }
}

// ---------------------------------------------------------------------------
// GEMM23: fused layers 2-4 (unchanged from R1, validated).
// ---------------------------------------------------------------------------
__global__ __launch_bounds__(256) void gemm23_kernel(
    const u16* __restrict__ h1, const u16* __restrict__ w2t, const float* __restrict__ b2,
    const u16* __restrict__ w3t, const float* __restrict__ b3,
    const float* __restrict__ w4, const float* __restrict__ b4, float* __restrict__ out) {
  __shared__ __align__(16) u16 At[128 * 32];
  __shared__ __align__(16) u16 Bt[128 * 32];
  __shared__ __align__(16) u16 B3[64 * 128];
  __shared__ __align__(16) u16 H2[128 * 136];
  const int tid = threadIdx.x, lane = tid & 63, wv = tid >> 6;
  const int l15 = lane & 15, q4 = lane >> 4;
  const int m0 = blockIdx.x * 128;

#pragma unroll
  for (int p = 0; p < 4; ++p) {
    int c = p * 256 + tid;
    *(uint4*)(B3 + c * 8) = *(const uint4*)(w3t + c * 8);
  }

  v4f acc[2][8];
#pragma unroll
  for (int mt = 0; mt < 2; ++mt)
#pragma unroll
    for (int nt = 0; nt < 8; ++nt)
#pragma unroll
      for (int r = 0; r < 4; ++r) acc[mt][nt][r] = 0.f;

  const int arow = tid >> 2, aq = tid & 3;
  for (int k0 = 0; k0 < 256; k0 += 32) {
    uint4 av[2], bv[2];
    av[0] = *(const uint4*)(h1 + (size_t)(m0 + arow) * 256 + k0 + aq * 8);
    av[1] = *(const uint4*)(h1 + (size_t)(m0 + 64 + arow) * 256 + k0 + aq * 8);
    bv[0] = *(const uint4*)(w2t + (size_t)arow * 256 + k0 + aq * 8);
    bv[1] = *(const uint4*)(w2t + (size_t)(64 + arow) * 256 + k0 + aq * 8);
    __syncthreads();
    *(uint4*)(At + tid * 8) = av[0];
    *(uint4*)(At + (256 + tid) * 8) = av[1];
    *(uint4*)(Bt + tid * 8) = bv[0];
    *(uint4*)(Bt + (256 + tid) * 8) = bv[1];
    __syncthreads();

    short8 af[2], bfr[8];
#pragma unroll
    for (int mt = 0; mt < 2; ++mt)
      af[mt] = *(const short8*)(At + (wv * 32 + mt * 16 + l15) * 32 + q4 * 8);
#pragma unroll
    for (int nt = 0; nt < 8; ++nt)
      bfr[nt] = *(const short8*)(Bt + (nt * 16 + l15) * 32 + q4 * 8);
#pragma unroll
    for (int mt = 0; mt < 2; ++mt)
#pragma unroll
      for (int nt = 0; nt < 8; ++nt)
        acc[mt][nt] = mfma16(af[mt], bfr[nt], acc[mt][nt]);
  }
  __syncthreads();
#pragma unroll
  for (int mt = 0; mt < 2; ++mt)
#pragma unroll
    for (int nt = 0; nt < 8; ++nt) {
      int c = nt * 16 + l15;
      float bias = b2[c];
#pragma unroll
      for (int r = 0; r < 4; ++r) {
        int rl = wv * 32 + mt * 16 + q4 * 4 + r;
        H2[rl * 136 + c] = f2bf(fmaxf(acc[mt][nt][r] + bias, 0.f));
      }
    }
  __syncthreads();

  v4f acc2[2][4];
#pragma unroll
  for (int mt = 0; mt < 2; ++mt)
#pragma unroll
    for (int nt = 0; nt < 4; ++nt)
#pragma unroll
      for (int r = 0; r < 4; ++r) acc2[mt][nt][r] = 0.f;
#pragma unroll
  for (int kk = 0; kk < 4; ++kk) {
    short8 af2[2], bf2[4];
#pragma unroll
    for (int mt = 0; mt < 2; ++mt)
      af2[mt] = *(const short8*)(H2 + (wv * 32 + mt * 16 + l15) * 136 + kk * 32 + q4 * 8);
#pragma unroll
    for (int nt = 0; nt < 4; ++nt)
      bf2[nt] = *(const short8*)(B3 + (nt * 16 + l15) * 128 + kk * 32 + q4 * 8);
#pragma unroll
    for (int mt = 0; mt < 2; ++mt)
#pragma unroll
      for (int nt = 0; nt < 4; ++nt)
        acc2[mt][nt] = mfma16(af2[mt], bf2[nt], acc2[mt][nt]);
  }

  float b4v = b4[0];
#pragma unroll
  for (int mt = 0; mt < 2; ++mt)
#pragma unroll
    for (int r = 0; r < 4; ++r) {
      float p = 0.f;
#pragma unroll
      for (int nt = 0; nt < 4; ++nt) {
        int c = nt * 16 + l15;
        float h3 = fmaxf(acc2[mt][nt][r] + b3[c], 0.f);
        p += h3 * w4[c];
      }
      p += __shfl_xor(p, 1);
      p += __shfl_xor(p, 2);
      p += __shfl_xor(p, 4);
      p += __shfl_xor(p, 8);
      if (l15 == 0) {
        int row = m0 + wv * 32 + mt * 16 + q4 * 4 + r;
        out[row] = p + b4v;
      }
    }
}

// ---------------------------------------------------------------------------
extern "C" void kernel_launch(void* const* d_in, const int* in_sizes, int n_in,
                              void* d_out, int out_size, void* d_ws, size_t ws_size,
                              hipStream_t stream) {
  const float* x  = (const float*)d_in[0];
  const float* W1 = (const float*)d_in[1];
  const float* b1 = (const float*)d_in[2];
  const float* W2 = (const float*)d_in[3];
  const float* b2 = (const float*)d_in[4];
  const float* W3 = (const float*)d_in[5];
  const float* b3 = (const float*)d_in[6];
  const float* W4 = (const float*)d_in[7];
  const float* b4 = (const float*)d_in[8];
  float* out = (float*)d_out;

  char* ws = (char*)d_ws;
  u16* feats = (u16*)ws;                                  // 65536*1824*2 = 239,075,328
  u16* h1    = (u16*)(ws + 239075328ull);                 // 65536*256*2  =  33,554,432
  u16* w1t   = (u16*)(ws + 239075328ull + 33554432ull);   // 256*1824*2   =     933,888
  u16* w2t   = (u16*)(ws + 239075328ull + 33554432ull + 933888ull);          // 65,536
  u16* w3t   = (u16*)(ws + 239075328ull + 33554432ull + 933888ull + 65536ull); // 16,384

  prep_kernel<<<1824, 256, 0, stream>>>(W1, W2, W3, w1t, w2t, w3t);
  feat_kernel<<<1024, 256, 0, stream>>>(x, feats);
  svd_kernel<<<1024, 64, 0, stream>>>(feats);
  gemm1_kernel<<<512, 256, 0, stream>>>(feats, w1t, b1, h1);
  gemm23_kernel<<<512, 256, 0, stream>>>(h1, w2t, b2, w3t, b3, W4, b4, out);
}

// Round 3
// 487.389 us; speedup vs baseline: 1.8371x; 1.2003x over previous
//
#include <hip/hip_runtime.h>
#include <hip/hip_bf16.h>
#include <cstdint>
#include <cstddef>

typedef unsigned short u16;
typedef unsigned int u32;
typedef short short8 __attribute__((ext_vector_type(8)));
typedef short short4v __attribute__((ext_vector_type(4)));
typedef __bf16 bf16x8 __attribute__((ext_vector_type(8)));
typedef float v4f __attribute__((ext_vector_type(4)));
typedef float v16f __attribute__((ext_vector_type(16)));

#define NSAMP 65536
#define FEAT_PAD 1824   // 57 * 32 (1808 padded; pad cols of W1t are zero)

// feats k-index layout (PERMUTED inside gram blocks; prep applies inverse to W1):
//   [0,512)     x, natural order
//   [512,1536)  gram32 in MFMA C-layout order: pos = 512 + lane*16 + r
//               <-> orig 512 + i*32 + j,  j=lane&31, i=(r&3)+8*(r>>2)+4*(lane>>5)
//   [1536,1792) gram16 in C-layout order:  pos = 1536 + lane*4 + r
//               <-> orig 1536 + i*16 + j,  j=lane&15, i=(lane>>4)*4+r
//   [1792,1808) singular values, natural order
//   [1808,1824) zeros

__device__ __forceinline__ u16 f2bf(float f) {
  union { float f; u32 u; } v; v.f = f;
  u32 r = (v.u + 0x7FFFu + ((v.u >> 16) & 1u)) >> 16;  // RTNE
  return (u16)r;
}
__device__ __forceinline__ float bf2f(u16 h) {
  union { u32 u; float f; } v; v.u = ((u32)h) << 16;
  return v.f;
}

__device__ __forceinline__ v4f mfma16(short8 a, short8 b, v4f c) {
  return __builtin_amdgcn_mfma_f32_16x16x32_bf16(
      __builtin_bit_cast(bf16x8, a), __builtin_bit_cast(bf16x8, b), c, 0, 0, 0);
}
__device__ __forceinline__ v16f mfma32(short8 a, short8 b, v16f c) {
  return __builtin_amdgcn_mfma_f32_32x32x16_bf16(
      __builtin_bit_cast(bf16x8, a), __builtin_bit_cast(bf16x8, b), c, 0, 0, 0);
}

// async global->LDS, 16 B per lane; LDS dest = wave-uniform base + lane*16
typedef __attribute__((address_space(1))) const void* gas_ptr;
typedef __attribute__((address_space(3))) void* las_ptr;
__device__ __forceinline__ void gl_lds16(const void* g, void* l) {
  __builtin_amdgcn_global_load_lds((gas_ptr)g, (las_ptr)l, 16, 0, 0);
}

// ---------------------------------------------------------------------------
// Weight prep: transpose + bf16-cast W1/W2/W3. W1t rows follow the permuted
// feats k-layout (see top-of-file map).
// ---------------------------------------------------------------------------
__global__ void prep_kernel(const float* __restrict__ W1, const float* __restrict__ W2,
                            const float* __restrict__ W3,
                            u16* __restrict__ w1t, u16* __restrict__ w2t, u16* __restrict__ w3t) {
  int idx = blockIdx.x * 256 + threadIdx.x;
  if (idx < 256 * FEAT_PAD) {
    int n = idx / FEAT_PAD, kp = idx % FEAT_PAD;
    int k;
    if (kp < 512) {
      k = kp;
    } else if (kp < 1536) {
      int t = kp - 512, ln = t >> 4, r = t & 15;
      int jj = ln & 31, q2 = ln >> 5;
      int i = (r & 3) + 8 * (r >> 2) + 4 * q2;
      k = 512 + i * 32 + jj;
    } else if (kp < 1792) {
      int t = kp - 1536, ln = t >> 2, r = t & 3;
      int jj = ln & 15;
      int i = (ln >> 4) * 4 + r;
      k = 1536 + i * 16 + jj;
    } else {
      k = kp;
    }
    w1t[idx] = (kp < 1808) ? f2bf(W1[(size_t)k * 256 + n]) : (u16)0;
  }
  if (idx < 128 * 256) {
    int n = idx / 256, k = idx % 256;
    w2t[idx] = f2bf(W2[k * 128 + n]);
  }
  if (idx < 64 * 128) {
    int n = idx / 128, k = idx % 128;
    w3t[idx] = f2bf(W3[k * 64 + n]);
  }
}

// ---------------------------------------------------------------------------
// Feature kernel: grams via MFMA, fragments stored CONTIGUOUSLY per lane
// (C-layout order) -> 2x short8 + 1x short4 instead of 20 scalar stores.
// ---------------------------------------------------------------------------
__global__ __launch_bounds__(256) void feat_kernel(const float* __restrict__ x,
                                                   u16* __restrict__ feats) {
  const int lane = threadIdx.x & 63;
  const int wid = ((blockIdx.x * 256) + threadIdx.x) >> 6;  // 0..4095
  const int l15 = lane & 15, l31 = lane & 31, q4 = lane >> 4, q2 = lane >> 5;
  const int pbase = l15 * 32 + q4 * 8;

  for (int it = 0; it < 16; ++it) {
    const int s = wid * 16 + it;
    const float* xs = x + (size_t)s * 512;
    float4 p0 = *(const float4*)(xs + pbase);
    float4 p1 = *(const float4*)(xs + pbase + 4);
    float t[8];
#pragma unroll
    for (int j = 0; j < 8; ++j) t[j] = xs[(q2 * 8 + j) * 32 + l31];

    short8 fp, ft;
    fp[0] = (short)f2bf(p0.x); fp[1] = (short)f2bf(p0.y);
    fp[2] = (short)f2bf(p0.z); fp[3] = (short)f2bf(p0.w);
    fp[4] = (short)f2bf(p1.x); fp[5] = (short)f2bf(p1.y);
    fp[6] = (short)f2bf(p1.z); fp[7] = (short)f2bf(p1.w);
#pragma unroll
    for (int j = 0; j < 8; ++j) ft[j] = (short)f2bf(t[j]);

    v4f accR; v16f accC;
#pragma unroll
    for (int r = 0; r < 4; ++r) accR[r] = 0.f;
#pragma unroll
    for (int r = 0; r < 16; ++r) accC[r] = 0.f;
    accR = mfma16(fp, fp, accR);   // Gr = P P^T
    accC = mfma32(ft, ft, accC);   // Gc = P^T P

    u16* fs = feats + (size_t)s * FEAT_PAD;
    *(short8*)(fs + pbase) = fp;   // x block

    short8 c0, c1;
#pragma unroll
    for (int r = 0; r < 8; ++r) { c0[r] = (short)f2bf(accC[r]); c1[r] = (short)f2bf(accC[r + 8]); }
    *(short8*)(fs + 512 + lane * 16) = c0;
    *(short8*)(fs + 512 + lane * 16 + 8) = c1;

    short4v r4;
#pragma unroll
    for (int r = 0; r < 4; ++r) r4[r] = (short)f2bf(accR[r]);
    *(short4v*)(fs + 1536 + lane * 4) = r4;

    if (lane < 2) {  // zero pad [1808,1824)
      short8 z;
#pragma unroll
      for (int j = 0; j < 8; ++j) z[j] = 0;
      *(short8*)(fs + 1808 + lane * 8) = z;
    }
  }
}

// ---------------------------------------------------------------------------
// SVD kernel, lane-parallel: 16 lanes per sample, lane j owns COLUMN j of the
// symmetric 16x16 gram in registers (all static indices -> no scratch).
// Householder tridiagonalization via shuffles, then 16 eigenvalues bisected
// in parallel (one per lane). sv[t] = sqrt(lambda[15-t]).
// ---------------------------------------------------------------------------
__global__ __launch_bounds__(256) void svd_kernel(u16* __restrict__ feats) {
  const int tid = threadIdx.x;
  const int lane = tid & 63;
  const int j = lane & 15;
  const int bse = lane & 48;                       // 16-lane group base
  const int w = (blockIdx.x * 256 + tid) >> 6;     // global wave id
  const int s = w * 4 + ((lane >> 4) & 3);         // sample id
  u16* fs = feats + (size_t)s * FEAT_PAD;

  // load column j (permuted gram16 layout: elem (i,j) at 1536+(i>>2)*64+j*4+(i&3))
  float a[16];
#pragma unroll
  for (int gi = 0; gi < 4; ++gi) {
    ushort4 v = *(const ushort4*)(fs + 1536 + gi * 64 + j * 4);
    a[gi * 4 + 0] = bf2f(v.x); a[gi * 4 + 1] = bf2f(v.y);
    a[gi * 4 + 2] = bf2f(v.z); a[gi * 4 + 3] = bf2f(v.w);
  }

  float es[16];
#pragma unroll
  for (int i = 0; i < 16; ++i) es[i] = 0.f;

#pragma unroll
  for (int step = 0; step < 14; ++step) {
    const int i = 15 - step, l = i - 1;
    float xv = a[i];                    // element (i, j): row i distributed
    float xm = (j <= l) ? xv : 0.f;
    float h = xm * xm;                  // group-reduce: h = sum_{j<=l} u_j^2
    h += __shfl_xor(h, 1); h += __shfl_xor(h, 2);
    h += __shfl_xor(h, 4); h += __shfl_xor(h, 8);
    float ul = __shfl(xm, bse + l);
    float sq = sqrtf(h);
    float alpha = (ul >= 0.f) ? -sq : sq;
    float denom = h - ul * alpha;       // >= h, no cancellation
    float beta = (h > 1e-30f) ? (1.0f / denom) : 0.f;
    float v = (j < l) ? xm : ((j == l) ? (xm - alpha) : 0.f);
    float vv[16], pp[16];
#pragma unroll
    for (int m = 0; m < 16; ++m) vv[m] = (m < i) ? __shfl(v, bse + m) : 0.f;
    float p = 0.f;                      // p_j = beta * sum_m A[m][j] v_m (symmetry)
#pragma unroll
    for (int m = 0; m < 16; ++m) if (m < i) p = fmaf(a[m], vv[m], p);
    p *= beta;
#pragma unroll
    for (int m = 0; m < 16; ++m) pp[m] = (m <= i) ? __shfl(p, bse + m) : 0.f;
    float Ks = 0.f;                     // K = beta/2 * p.v
#pragma unroll
    for (int m = 0; m < 16; ++m) if (m < i) Ks = fmaf(pp[m], vv[m], Ks);
    Ks *= 0.5f * beta;
    float wsc = p - Ks * v;
#pragma unroll
    for (int m = 0; m <= 15; ++m) {     // A <- A - v w^T - w v^T (m>i exact no-op)
      if (m <= i) {
        float wm = pp[m] - Ks * vv[m];
        a[m] -= vv[m] * wsc + wm * v;
      }
    }
    es[i] = alpha;                      // uniform within group
  }
  es[1] = __shfl(a[1], bse + 0);        // A[1][0]

  // diagonal: d_j = a[j] via static selects, then broadcast full d to all lanes
  float dsel = a[0];
#pragma unroll
  for (int m = 1; m < 16; ++m) dsel = (j == m) ? a[m] : dsel;
  float dd[16];
#pragma unroll
  for (int m = 0; m < 16; ++m) dd[m] = __shfl(dsel, bse + m);
  float e2a[16];
  e2a[0] = 0.f;
#pragma unroll
  for (int k = 1; k < 16; ++k) e2a[k] = es[k] * es[k] + 1e-30f;
  float dmax = dd[0], emax = 0.f;
#pragma unroll
  for (int m = 1; m < 16; ++m) dmax = fmaxf(dmax, dd[m]);
#pragma unroll
  for (int k = 1; k < 16; ++k) emax = fmaxf(emax, fabsf(es[k]));
  float lo = 0.f, hi = dmax + 2.f * emax + 1e-6f;   // PSD: lower bound 0
#pragma unroll 1
  for (int iter = 0; iter < 15; ++iter) {
    float mid = 0.5f * (lo + hi);
    float q = dd[0] - mid;
    int cnt = (q < 0.f) ? 1 : 0;
#pragma unroll
    for (int k = 1; k < 16; ++k) {
      q = dd[k] - mid - e2a[k] * __builtin_amdgcn_rcpf(q);
      cnt += (q < 0.f) ? 1 : 0;
    }
    if (cnt > j) hi = mid; else lo = mid;  // lane j -> j-th smallest eigenvalue
  }
  float lam = 0.5f * (lo + hi);
  fs[1792 + (15 - j)] = f2bf(sqrtf(fmaxf(lam, 0.f)));
}

// ---------------------------------------------------------------------------
// GEMM1: h1 = relu(feats @ W1 + b1).  M=65536, K=1824, N=256. (unchanged R2)
// ---------------------------------------------------------------------------
__global__ __launch_bounds__(256, 2) void gemm1_kernel(const u16* __restrict__ feats,
                                                       const u16* __restrict__ w1t,
                                                       const float* __restrict__ b1,
                                                       u16* __restrict__ h1) {
  __shared__ __align__(16) u16 At[4 * 128 * 8];   // 8 KB
  __shared__ __align__(16) u16 Bt[4 * 256 * 8];   // 16 KB
  const int tid = threadIdx.x, lane = tid & 63, wv = tid >> 6;
  const int l15 = lane & 15, q4 = lane >> 4;
  const int m0 = blockIdx.x * 128;
  const int wm = (wv & 1) * 64, wn = (wv >> 1) * 128;

  const u16* gA[2]; u16* lA[2];
#pragma unroll
  for (int j = 0; j < 2; ++j) {
    int slot0 = (wv * 2 + j) * 64, slot = slot0 + lane;
    int q = slot >> 7, row = slot & 127;
    gA[j] = feats + (size_t)(m0 + row) * FEAT_PAD + q * 8;
    lA[j] = At + slot0 * 8;
  }
  const u16* gB[4]; u16* lB[4];
#pragma unroll
  for (int j = 0; j < 4; ++j) {
    int slot0 = (wv * 4 + j) * 64, slot = slot0 + lane;
    int q = slot >> 8, col = slot & 255;
    gB[j] = w1t + (size_t)col * FEAT_PAD + q * 8;
    lB[j] = Bt + slot0 * 8;
  }

  v4f acc[4][8];
#pragma unroll
  for (int mt = 0; mt < 4; ++mt)
#pragma unroll
    for (int nt = 0; nt < 8; ++nt)
#pragma unroll
      for (int r = 0; r < 4; ++r) acc[mt][nt][r] = 0.f;

  for (int k0 = 0; k0 < FEAT_PAD; k0 += 32) {
#pragma unroll
    for (int j = 0; j < 2; ++j) gl_lds16(gA[j] + k0, lA[j]);
#pragma unroll
    for (int j = 0; j < 4; ++j) gl_lds16(gB[j] + k0, lB[j]);
    __syncthreads();

    short8 af[4], bfr[8];
#pragma unroll
    for (int mt = 0; mt < 4; ++mt)
      af[mt] = *(const short8*)(At + (q4 * 128 + wm + mt * 16 + l15) * 8);
#pragma unroll
    for (int nt = 0; nt < 8; ++nt)
      bfr[nt] = *(const short8*)(Bt + (q4 * 256 + wn + nt * 16 + l15) * 8);
#pragma unroll
    for (int mt = 0; mt < 4; ++mt)
#pragma unroll
      for (int nt = 0; nt < 8; ++nt)
        acc[mt][nt] = mfma16(af[mt], bfr[nt], acc[mt][nt]);
    __syncthreads();
  }

#pragma unroll
  for (int mt = 0; mt < 4; ++mt)
#pragma unroll
    for (int nt = 0; nt < 8; ++nt) {
      int col = wn + nt * 16 + l15;
      float bias = b1[col];
#pragma unroll
      for (int r = 0; r < 4; ++r) {
        int row = m0 + wm + mt * 16 + q4 * 4 + r;
        h1[(size_t)row * 256 + col] = f2bf(fmaxf(acc[mt][nt][r] + bias, 0.f));
      }
    }
}

// ---------------------------------------------------------------------------
// GEMM23: fused layers 2-4 (unchanged, validated).
// ---------------------------------------------------------------------------
__global__ __launch_bounds__(256) void gemm23_kernel(
    const u16* __restrict__ h1, const u16* __restrict__ w2t, const float* __restrict__ b2,
    const u16* __restrict__ w3t, const float* __restrict__ b3,
    const float* __restrict__ w4, const float* __restrict__ b4, float* __restrict__ out) {
  __shared__ __align__(16) u16 At[128 * 32];
  __shared__ __align__(16) u16 Bt[128 * 32];
  __shared__ __align__(16) u16 B3[64 * 128];
  __shared__ __align__(16) u16 H2[128 * 136];
  const int tid = threadIdx.x, lane = tid & 63, wv = tid >> 6;
  const int l15 = lane & 15, q4 = lane >> 4;
  const int m0 = blockIdx.x * 128;

#pragma unroll
  for (int p = 0; p < 4; ++p) {
    int c = p * 256 + tid;
    *(uint4*)(B3 + c * 8) = *(const uint4*)(w3t + c * 8);
  }

  v4f acc[2][8];
#pragma unroll
  for (int mt = 0; mt < 2; ++mt)
#pragma unroll
    for (int nt = 0; nt < 8; ++nt)
#pragma unroll
      for (int r = 0; r < 4; ++r) acc[mt][nt][r] = 0.f;

  const int arow = tid >> 2, aq = tid & 3;
  for (int k0 = 0; k0 < 256; k0 += 32) {
    uint4 av[2], bv[2];
    av[0] = *(const uint4*)(h1 + (size_t)(m0 + arow) * 256 + k0 + aq * 8);
    av[1] = *(const uint4*)(h1 + (size_t)(m0 + 64 + arow) * 256 + k0 + aq * 8);
    bv[0] = *(const uint4*)(w2t + (size_t)arow * 256 + k0 + aq * 8);
    bv[1] = *(const uint4*)(w2t + (size_t)(64 + arow) * 256 + k0 + aq * 8);
    __syncthreads();
    *(uint4*)(At + tid * 8) = av[0];
    *(uint4*)(At + (256 + tid) * 8) = av[1];
    *(uint4*)(Bt + tid * 8) = bv[0];
    *(uint4*)(Bt + (256 + tid) * 8) = bv[1];
    __syncthreads();

    short8 af[2], bfr[8];
#pragma unroll
    for (int mt = 0; mt < 2; ++mt)
      af[mt] = *(const short8*)(At + (wv * 32 + mt * 16 + l15) * 32 + q4 * 8);
#pragma unroll
    for (int nt = 0; nt < 8; ++nt)
      bfr[nt] = *(const short8*)(Bt + (nt * 16 + l15) * 32 + q4 * 8);
#pragma unroll
    for (int mt = 0; mt < 2; ++mt)
#pragma unroll
      for (int nt = 0; nt < 8; ++nt)
        acc[mt][nt] = mfma16(af[mt], bfr[nt], acc[mt][nt]);
  }
  __syncthreads();
#pragma unroll
  for (int mt = 0; mt < 2; ++mt)
#pragma unroll
    for (int nt = 0; nt < 8; ++nt) {
      int c = nt * 16 + l15;
      float bias = b2[c];
#pragma unroll
      for (int r = 0; r < 4; ++r) {
        int rl = wv * 32 + mt * 16 + q4 * 4 + r;
        H2[rl * 136 + c] = f2bf(fmaxf(acc[mt][nt][r] + bias, 0.f));
      }
    }
  __syncthreads();

  v4f acc2[2][4];
#pragma unroll
  for (int mt = 0; mt < 2; ++mt)
#pragma unroll
    for (int nt = 0; nt < 4; ++nt)
#pragma unroll
      for (int r = 0; r < 4; ++r) acc2[mt][nt][r] = 0.f;
#pragma unroll
  for (int kk = 0; kk < 4; ++kk) {
    short8 af2[2], bf2v[4];
#pragma unroll
    for (int mt = 0; mt < 2; ++mt)
      af2[mt] = *(const short8*)(H2 + (wv * 32 + mt * 16 + l15) * 136 + kk * 32 + q4 * 8);
#pragma unroll
    for (int nt = 0; nt < 4; ++nt)
      bf2v[nt] = *(const short8*)(B3 + (nt * 16 + l15) * 128 + kk * 32 + q4 * 8);
#pragma unroll
    for (int mt = 0; mt < 2; ++mt)
#pragma unroll
      for (int nt = 0; nt < 4; ++nt)
        acc2[mt][nt] = mfma16(af2[mt], bf2v[nt], acc2[mt][nt]);
  }

  float b4v = b4[0];
#pragma unroll
  for (int mt = 0; mt < 2; ++mt)
#pragma unroll
    for (int r = 0; r < 4; ++r) {
      float p = 0.f;
#pragma unroll
      for (int nt = 0; nt < 4; ++nt) {
        int c = nt * 16 + l15;
        float h3 = fmaxf(acc2[mt][nt][r] + b3[c], 0.f);
        p += h3 * w4[c];
      }
      p += __shfl_xor(p, 1);
      p += __shfl_xor(p, 2);
      p += __shfl_xor(p, 4);
      p += __shfl_xor(p, 8);
      if (l15 == 0) {
        int row = m0 + wv * 32 + mt * 16 + q4 * 4 + r;
        out[row] = p + b4v;
      }
    }
}

// ---------------------------------------------------------------------------
extern "C" void kernel_launch(void* const* d_in, const int* in_sizes, int n_in,
                              void* d_out, int out_size, void* d_ws, size_t ws_size,
                              hipStream_t stream) {
  const float* x  = (const float*)d_in[0];
  const float* W1 = (const float*)d_in[1];
  const float* b1 = (const float*)d_in[2];
  const float* W2 = (const float*)d_in[3];
  const float* b2 = (const float*)d_in[4];
  const float* W3 = (const float*)d_in[5];
  const float* b3 = (const float*)d_in[6];
  const float* W4 = (const float*)d_in[7];
  const float* b4 = (const float*)d_in[8];
  float* out = (float*)d_out;

  char* ws = (char*)d_ws;
  u16* feats = (u16*)ws;                                  // 65536*1824*2 = 239,075,328
  u16* h1    = (u16*)(ws + 239075328ull);                 // 65536*256*2  =  33,554,432
  u16* w1t   = (u16*)(ws + 239075328ull + 33554432ull);   // 256*1824*2   =     933,888
  u16* w2t   = (u16*)(ws + 239075328ull + 33554432ull + 933888ull);          // 65,536
  u16* w3t   = (u16*)(ws + 239075328ull + 33554432ull + 933888ull + 65536ull); // 16,384

  prep_kernel<<<1824, 256, 0, stream>>>(W1, W2, W3, w1t, w2t, w3t);
  feat_kernel<<<1024, 256, 0, stream>>>(x, feats);
  svd_kernel<<<4096, 256, 0, stream>>>(feats);
  gemm1_kernel<<<512, 256, 0, stream>>>(feats, w1t, b1, h1);
  gemm23_kernel<<<512, 256, 0, stream>>>(h1, w2t, b2, w3t, b3, W4, b4, out);
}